// Round 6
// baseline (189.657 us; speedup 1.0000x reference)
//
#include <hip/hip_runtime.h>

typedef __attribute__((ext_vector_type(8))) short bf16x8;
typedef __attribute__((ext_vector_type(4))) float f32x4;

// ---------------------------------------------------------------------------
// Posit(8,1) round-to-nearest posit quantization, bit-exact vs jnp reference.
// ---------------------------------------------------------------------------
__device__ __forceinline__ float posit_q(float x) {
  float ax = fabsf(x);
  ax = fmaxf(ax, 0x1p-12f);
  ax = fminf(ax, 0x1p12f);
  int s = (int)(__float_as_uint(ax) >> 23) - 127;   // floor(log2(ax)), exact
  int k = s >> 1;                                   // floor(s/2)
  int rlen = (k >= 0) ? (k + 2) : (1 - k);
  int fbits = 6 - rlen;
  fbits = fbits < 0 ? 0 : fbits;
  float m = ax * __uint_as_float((unsigned)(127 - s) << 23);  // [1,2)
  float fs = (float)(1 << fbits);
  float inv_fs = __uint_as_float((unsigned)(127 - fbits) << 23);
  float mq = rintf(m * fs) * inv_fs;                // round-half-even = jnp.round
  if (mq >= 2.0f) { s += 1; mq = 1.0f; }            // mantissa carry
  float y = mq * __uint_as_float((unsigned)(127 + s) << 23);
  y = fminf(y, 0x1p12f);
  y = copysignf(y, x);
  return (x == 0.0f) ? 0.0f : y;
}

__device__ __forceinline__ ushort4 quant4_bf16(float4 v) {
  ushort4 o;
  o.x = (ushort)(__float_as_uint(posit_q(v.x)) >> 16);
  o.y = (ushort)(__float_as_uint(posit_q(v.y)) >> 16);
  o.z = (ushort)(__float_as_uint(posit_q(v.z)) >> 16);
  o.w = (ushort)(__float_as_uint(posit_q(v.w)) >> 16);
  return o;
}

__global__ void posit_quant_all(const float* __restrict__ x,
                                const float* __restrict__ w,
                                const float* __restrict__ b,
                                ushort* __restrict__ Xq,
                                ushort* __restrict__ Wq,
                                float* __restrict__ bq,
                                int nx4, int nw4, int nb4) {
  int i = blockIdx.x * blockDim.x + threadIdx.x;
  if (i < nx4) {
    ((ushort4*)Xq)[i] = quant4_bf16(((const float4*)x)[i]);
  } else if (i < nx4 + nw4) {
    int j = i - nx4;
    ((ushort4*)Wq)[j] = quant4_bf16(((const float4*)w)[j]);
  } else if (i < nx4 + nw4 + nb4) {
    int j = i - nx4 - nw4;
    float4 v = ((const float4*)b)[j];
    float4 o;
    o.x = posit_q(v.x); o.y = posit_q(v.y);
    o.z = posit_q(v.z); o.w = posit_q(v.w);
    ((float4*)bq)[j] = o;
  }
}

// ---------------------------------------------------------------------------
// R11 = R10 skeleton (256x256, BK=32, 5 x 32KB buffers = 160 KiB, one
// s_barrier + one counted vmcnt per step, depth-3 prefetch) with the wave
// geometry changed to 1024 threads = 16 waves (4x4 grid, 64x64 out/wave).
//
// Rationale (R5..R10 ingest data): global->LDS ingest is a RATE limit that
// correlates with the number of load-issuing waves per CU: 16 waves (R5/R8)
// -> ~19 B/cyc; my 8-wave 1-block schedules (R9/R10) -> ~12 B/cyc regardless
// of pipeline depth (depth-2 -> depth-3 moved it 4%). R11 restores 16
// staging waves while keeping the 256^2 tile's 2.1 MB/CU staged bytes
// (R5 staged 3.1). Per-wave resource shape == R5 (acc[4][4] = 64 AGPR,
// fa[4]/fb[4]; R5 compiled to 60 VGPR) -> fits the 128-reg/wave budget at
// 16 waves/CU, proven by R5 itself.
//
// Pipeline (per-wave FIFO, 2 gl_lds per wave per step):
//   prologue: stage t0,t1,t2 (6 outstanding); vmcnt(4) retires t0; BAR.
//   step t (t < T-3): STAGE(t+3) -> {t+1,t+2,t+3}=6; vmcnt(4) retires t+1;
//     BAR (collective: after it, ALL waves' t+1 loads are in LDS); COMP(t).
//   tail: t=T-3 no wait (retired at step T-4); t=T-2 vmcnt(2)+BAR;
//     t=T-1 vmcnt(0)+BAR. Never drains to 0 mid-loop (T4).
// WAR: STAGE(t+3) targets buf[(t-2)%5], last read in COMP(t-2); all waves
// passed BAR(t-1) which is after their COMP(t-2) in program order.
//
// Swizzle (R10-verified, 0 conflicts): chunk p of row r stored at slot
// p ^ ((r>>1)&3), pre-applied to the GLOBAL source (LDS dests lane-linear
// as global_load_lds requires). Read slot t4 ^ ((fr>>1)&3) (row terms
// wm*64, wn*64, i*16 all == 0 mod 8 -> lane-uniform across fragments).
// ---------------------------------------------------------------------------
__device__ __forceinline__ void gl_lds16(const ushort* g, ushort* l) {
  __builtin_amdgcn_global_load_lds(
      (const __attribute__((address_space(1))) void*)g,
      (__attribute__((address_space(3))) void*)l,
      16, 0, 0);
}

#define BAR() do { __builtin_amdgcn_s_barrier(); \
                   __builtin_amdgcn_sched_barrier(0); } while (0)

__global__ __launch_bounds__(1024, 4) void posit_gemm(
    const ushort* __restrict__ A, const ushort* __restrict__ B,
    const float* __restrict__ bq, float* __restrict__ C,
    int M, int N, int K) {
  __shared__ ushort lds[81920];   // 160 KiB: 5 buffers x 16384 elems (A|B 8192)

  const int tid = threadIdx.x;
  const int wave = tid >> 6;        // 0..15
  const int lane = tid & 63;
  const int wm = wave >> 2;         // 0..3 : 64-row slab
  const int wn = wave & 3;          // 0..3 : 64-col slab
  const int m0 = blockIdx.y << 8;
  const int n0 = blockIdx.x << 8;

  // --- staging: one A + one B instruction per wave per step; instruction
  // covers 16 rows (wave*16 + lane>>2), 4 lanes per row = 4 chunks of 8.
  // Source chunk pre-swizzled: (lane&3) ^ ((row>>1)&3) = (lane&3)^((lane>>3)&3).
  const int srow = (wave << 4) + (lane >> 2);         // 0..255
  const int sk = (((lane & 3) ^ ((lane >> 3) & 3)) << 3);
  const ushort* Ag = A + (size_t)(m0 + srow) * K + sk;
  const ushort* Bg = B + (size_t)(n0 + srow) * K + sk;
  const int sbase = wave << 9;                        // wave*512 elems

#define STAGE(Lb, kt) do {                                         \
    gl_lds16(Ag + ((size_t)(kt) << 5), (Lb) + sbase);              \
    gl_lds16(Bg + ((size_t)(kt) << 5), (Lb) + 8192 + sbase);       \
  } while (0)

  // --- fragment reads: row = slab + i*16 + fr; needed chunk t4 at slot
  // t4 ^ ((fr>>1)&3).
  const int fr = lane & 15;
  const int t4 = lane >> 4;                           // 0..3
  const int sl = ((t4 ^ ((fr >> 1) & 3)) << 3);
  const int arl = (((wm << 6) + fr) << 5) + sl;        // + i*512
  const int brl = (((wn << 6) + fr) << 5) + sl + 8192; // + j*512

  f32x4 acc[4][4];
#pragma unroll
  for (int i = 0; i < 4; i++)
#pragma unroll
    for (int j = 0; j < 4; j++) acc[i][j] = (f32x4){0.f, 0.f, 0.f, 0.f};

#define COMP(Lb) do {                                              \
    bf16x8 fa[4], fb[4];                                           \
    _Pragma("unroll")                                              \
    for (int i = 0; i < 4; i++)                                    \
      fa[i] = *(const bf16x8*)((Lb) + arl + (i << 9));             \
    _Pragma("unroll")                                              \
    for (int j = 0; j < 4; j++)                                    \
      fb[j] = *(const bf16x8*)((Lb) + brl + (j << 9));             \
    _Pragma("unroll")                                              \
    for (int i = 0; i < 4; i++)                                    \
      _Pragma("unroll")                                            \
      for (int j = 0; j < 4; j++)                                  \
        acc[i][j] = __builtin_amdgcn_mfma_f32_16x16x32_bf16(       \
            fa[i], fb[j], acc[i][j], 0, 0, 0);                     \
  } while (0)

  const int T = K >> 5;               // 64 K-steps of 32

  // ---- prologue: t0->buf0, t1->buf1, t2->buf2; retire t0; barrier.
  STAGE(lds,         0);
  STAGE(lds + 16384, 1);
  STAGE(lds + 32768, 2);
  asm volatile("s_waitcnt vmcnt(4)" ::: "memory");
  BAR();

  int cbi = 0;                        // t   mod 5 (compute buffer)
  int sbi = 3;                        // t+3 mod 5 (stage target)
#pragma unroll 1
  for (int t = 0; t < T - 3; ++t) {
    ushort* const cb = lds + (cbi << 14);
    ushort* const sb = lds + (sbi << 14);
    STAGE(sb, t + 3);
    asm volatile("s_waitcnt vmcnt(4)" ::: "memory");  // t+1 retired; {t+2,t+3} in flight
    BAR();
    COMP(cb);
    cbi = (cbi == 4) ? 0 : cbi + 1;
    sbi = (sbi == 4) ? 0 : sbi + 1;
  }
  // ---- tail: T-3 (already retired at step T-4), T-2, T-1
  {
    ushort* const cb = lds + (cbi << 14);
    COMP(cb);
    cbi = (cbi == 4) ? 0 : cbi + 1;
  }
  {
    ushort* const cb = lds + (cbi << 14);
    asm volatile("s_waitcnt vmcnt(2)" ::: "memory");
    BAR();
    COMP(cb);
    cbi = (cbi == 4) ? 0 : cbi + 1;
  }
  {
    ushort* const cb = lds + (cbi << 14);
    asm volatile("s_waitcnt vmcnt(0)" ::: "memory");
    BAR();
    COMP(cb);
  }

  // Epilogue: C/D layout col = lane&15, row = (lane>>4)*4 + reg. Fuse bias.
  const int row0 = m0 + (wm << 6) + (t4 << 2);
  const int col0 = n0 + (wn << 6) + fr;
#pragma unroll
  for (int j = 0; j < 4; j++) {
    const int col = col0 + (j << 4);
    const float bv = bq[col];
#pragma unroll
    for (int i = 0; i < 4; i++) {
      const int row = row0 + (i << 4);
#pragma unroll
      for (int r = 0; r < 4; r++)
        C[(size_t)(row + r) * N + col] = acc[i][j][r] + bv;
    }
  }
}

extern "C" void kernel_launch(void* const* d_in, const int* in_sizes, int n_in,
                              void* d_out, int out_size, void* d_ws, size_t ws_size,
                              hipStream_t stream) {
  const float* x = (const float*)d_in[0];
  const float* w = (const float*)d_in[1];
  const float* bias = (const float*)d_in[2];
  float* out = (float*)d_out;

  const int out_f = in_sizes[2];                 // 2048
  const int in_f = in_sizes[1] / out_f;          // 2048
  const int m = in_sizes[0] / in_f;              // 8192
  const int k = in_f;

  // workspace layout: Xq bf16 | Wq bf16 | bq fp32
  ushort* Xq = (ushort*)d_ws;
  ushort* Wq = Xq + (size_t)m * k;
  float* bquant = (float*)(Wq + (size_t)out_f * k);

  const int nx4 = in_sizes[0] / 4;
  const int nw4 = in_sizes[1] / 4;
  const int nb4 = in_sizes[2] / 4;
  const int total4 = nx4 + nw4 + nb4;
  posit_quant_all<<<(total4 + 255) / 256, 256, 0, stream>>>(
      x, w, bias, Xq, Wq, bquant, nx4, nw4, nb4);

  dim3 grid(out_f / 256, m / 256);
  posit_gemm<<<grid, 1024, 0, stream>>>(Xq, Wq, bquant, out, m, out_f, k);
}

// Round 7
// 184.029 us; speedup vs baseline: 1.0306x; 1.0306x over previous
//
#include <hip/hip_runtime.h>

typedef __attribute__((ext_vector_type(8))) short bf16x8;
typedef __attribute__((ext_vector_type(4))) float f32x4;

// ---------------------------------------------------------------------------
// Posit(8,1) round-to-nearest posit quantization, bit-exact vs jnp reference.
// ---------------------------------------------------------------------------
__device__ __forceinline__ float posit_q(float x) {
  float ax = fabsf(x);
  ax = fmaxf(ax, 0x1p-12f);
  ax = fminf(ax, 0x1p12f);
  int s = (int)(__float_as_uint(ax) >> 23) - 127;   // floor(log2(ax)), exact
  int k = s >> 1;                                   // floor(s/2)
  int rlen = (k >= 0) ? (k + 2) : (1 - k);
  int fbits = 6 - rlen;
  fbits = fbits < 0 ? 0 : fbits;
  float m = ax * __uint_as_float((unsigned)(127 - s) << 23);  // [1,2)
  float fs = (float)(1 << fbits);
  float inv_fs = __uint_as_float((unsigned)(127 - fbits) << 23);
  float mq = rintf(m * fs) * inv_fs;                // round-half-even = jnp.round
  if (mq >= 2.0f) { s += 1; mq = 1.0f; }            // mantissa carry
  float y = mq * __uint_as_float((unsigned)(127 + s) << 23);
  y = fminf(y, 0x1p12f);
  y = copysignf(y, x);
  return (x == 0.0f) ? 0.0f : y;
}

__device__ __forceinline__ ushort4 quant4_bf16(float4 v) {
  ushort4 o;
  o.x = (ushort)(__float_as_uint(posit_q(v.x)) >> 16);
  o.y = (ushort)(__float_as_uint(posit_q(v.y)) >> 16);
  o.z = (ushort)(__float_as_uint(posit_q(v.z)) >> 16);
  o.w = (ushort)(__float_as_uint(posit_q(v.w)) >> 16);
  return o;
}

__global__ void posit_quant_all(const float* __restrict__ x,
                                const float* __restrict__ w,
                                const float* __restrict__ b,
                                ushort* __restrict__ Xq,
                                ushort* __restrict__ Wq,
                                float* __restrict__ bq,
                                int nx4, int nw4, int nb4) {
  int i = blockIdx.x * blockDim.x + threadIdx.x;
  if (i < nx4) {
    ((ushort4*)Xq)[i] = quant4_bf16(((const float4*)x)[i]);
  } else if (i < nx4 + nw4) {
    int j = i - nx4;
    ((ushort4*)Wq)[j] = quant4_bf16(((const float4*)w)[j]);
  } else if (i < nx4 + nw4 + nb4) {
    int j = i - nx4 - nw4;
    float4 v = ((const float4*)b)[j];
    float4 o;
    o.x = posit_q(v.x); o.y = posit_q(v.y);
    o.z = posit_q(v.z); o.w = posit_q(v.w);
    ((float4*)bq)[j] = o;
  }
}

// ---------------------------------------------------------------------------
// R12 = R11 (256x256, BK=32, 5 x 32KB buffers, depth-3 prefetch, one
// s_barrier + one counted vmcnt per step, 1024 thr = 16 waves 4x4) plus
// T1 XCD-aware block mapping.
//
// Why: FETCH_SIZE (L2-miss traffic) = 135 MB vs ~40 MB unique input. Default
// x-fastest dispatch round-robins the 8 col-tiles of each row-tile (which
// share one 1 MB A-panel) across the 8 XCDs -> every A-panel is L2-filled up
// to 8x. Remap so each XCD owns a 4-row x 8-col patch of the 8x32 tile grid:
//   flat = by*8+bx (HW dispatch order); xcd = flat&7; r = flat>>3;
//   by' = xcd*4 + (r&3); bx' = r>>2.
// Per-XCD working set = 4 A-panels + 8 B-panels = 12 MB -> total L2 fills
// ~96 MB, staging hits L2 (~200cyc) instead of L3/HBM (~900cyc), shortening
// the exposed prefetch path. Bijective over the full 256-block grid.
//
// Pipeline (R11-verified): prologue stages t0..t2, vmcnt(4), BAR; step t:
// STAGE(t+3); vmcnt(4) retires t+1; BAR; COMP(t). Tail: none / vmcnt(2) /
// vmcnt(0). WAR: stage target buf[(t-2)%5] last read in COMP(t-2), ordered
// by BAR(t-1). Swizzle (0 conflicts, R10/R11-verified): chunk p of row r at
// slot p ^ ((r>>1)&3), pre-applied to the GLOBAL source.
// ---------------------------------------------------------------------------
__device__ __forceinline__ void gl_lds16(const ushort* g, ushort* l) {
  __builtin_amdgcn_global_load_lds(
      (const __attribute__((address_space(1))) void*)g,
      (__attribute__((address_space(3))) void*)l,
      16, 0, 0);
}

#define BAR() do { __builtin_amdgcn_s_barrier(); \
                   __builtin_amdgcn_sched_barrier(0); } while (0)

__global__ __launch_bounds__(1024, 4) void posit_gemm(
    const ushort* __restrict__ A, const ushort* __restrict__ B,
    const float* __restrict__ bq, float* __restrict__ C,
    int M, int N, int K) {
  __shared__ ushort lds[81920];   // 160 KiB: 5 buffers x 16384 elems (A|B 8192)

  const int tid = threadIdx.x;
  const int wave = tid >> 6;        // 0..15
  const int lane = tid & 63;
  const int wm = wave >> 2;         // 0..3 : 64-row slab
  const int wn = wave & 3;          // 0..3 : 64-col slab

  // T1: XCD patch mapping (grid 8x32, flat id x-fastest, xcd = flat&7)
  const int flat = (blockIdx.y << 3) | blockIdx.x;
  const int xcd = flat & 7;
  const int rr = flat >> 3;                 // 0..31
  const int m0 = ((xcd << 2) + (rr & 3)) << 8;   // row-tile 4*xcd + r%4
  const int n0 = (rr >> 2) << 8;                 // col-tile r/4

  // --- staging: one A + one B instruction per wave per step; instruction
  // covers 16 rows (wave*16 + lane>>2), 4 lanes per row = 4 chunks of 8.
  // Source chunk pre-swizzled: (lane&3) ^ ((row>>1)&3) = (lane&3)^((lane>>3)&3).
  const int srow = (wave << 4) + (lane >> 2);         // 0..255
  const int sk = (((lane & 3) ^ ((lane >> 3) & 3)) << 3);
  const ushort* Ag = A + (size_t)(m0 + srow) * K + sk;
  const ushort* Bg = B + (size_t)(n0 + srow) * K + sk;
  const int sbase = wave << 9;                        // wave*512 elems

#define STAGE(Lb, kt) do {                                         \
    gl_lds16(Ag + ((size_t)(kt) << 5), (Lb) + sbase);              \
    gl_lds16(Bg + ((size_t)(kt) << 5), (Lb) + 8192 + sbase);       \
  } while (0)

  // --- fragment reads: row = slab + i*16 + fr; needed chunk t4 at slot
  // t4 ^ ((fr>>1)&3).
  const int fr = lane & 15;
  const int t4 = lane >> 4;                           // 0..3
  const int sl = ((t4 ^ ((fr >> 1) & 3)) << 3);
  const int arl = (((wm << 6) + fr) << 5) + sl;        // + i*512
  const int brl = (((wn << 6) + fr) << 5) + sl + 8192; // + j*512

  f32x4 acc[4][4];
#pragma unroll
  for (int i = 0; i < 4; i++)
#pragma unroll
    for (int j = 0; j < 4; j++) acc[i][j] = (f32x4){0.f, 0.f, 0.f, 0.f};

#define COMP(Lb) do {                                              \
    bf16x8 fa[4], fb[4];                                           \
    _Pragma("unroll")                                              \
    for (int i = 0; i < 4; i++)                                    \
      fa[i] = *(const bf16x8*)((Lb) + arl + (i << 9));             \
    _Pragma("unroll")                                              \
    for (int j = 0; j < 4; j++)                                    \
      fb[j] = *(const bf16x8*)((Lb) + brl + (j << 9));             \
    _Pragma("unroll")                                              \
    for (int i = 0; i < 4; i++)                                    \
      _Pragma("unroll")                                            \
      for (int j = 0; j < 4; j++)                                  \
        acc[i][j] = __builtin_amdgcn_mfma_f32_16x16x32_bf16(       \
            fa[i], fb[j], acc[i][j], 0, 0, 0);                     \
  } while (0)

  const int T = K >> 5;               // 64 K-steps of 32

  // ---- prologue: t0->buf0, t1->buf1, t2->buf2; retire t0; barrier.
  STAGE(lds,         0);
  STAGE(lds + 16384, 1);
  STAGE(lds + 32768, 2);
  asm volatile("s_waitcnt vmcnt(4)" ::: "memory");
  BAR();

  int cbi = 0;                        // t   mod 5 (compute buffer)
  int sbi = 3;                        // t+3 mod 5 (stage target)
#pragma unroll 1
  for (int t = 0; t < T - 3; ++t) {
    ushort* const cb = lds + (cbi << 14);
    ushort* const sb = lds + (sbi << 14);
    STAGE(sb, t + 3);
    asm volatile("s_waitcnt vmcnt(4)" ::: "memory");  // t+1 retired; {t+2,t+3} in flight
    BAR();
    COMP(cb);
    cbi = (cbi == 4) ? 0 : cbi + 1;
    sbi = (sbi == 4) ? 0 : sbi + 1;
  }
  // ---- tail: T-3 (already retired at step T-4), T-2, T-1
  {
    ushort* const cb = lds + (cbi << 14);
    COMP(cb);
    cbi = (cbi == 4) ? 0 : cbi + 1;
  }
  {
    ushort* const cb = lds + (cbi << 14);
    asm volatile("s_waitcnt vmcnt(2)" ::: "memory");
    BAR();
    COMP(cb);
    cbi = (cbi == 4) ? 0 : cbi + 1;
  }
  {
    ushort* const cb = lds + (cbi << 14);
    asm volatile("s_waitcnt vmcnt(0)" ::: "memory");
    BAR();
    COMP(cb);
  }

  // Epilogue: C/D layout col = lane&15, row = (lane>>4)*4 + reg. Fuse bias.
  const int row0 = m0 + (wm << 6) + (t4 << 2);
  const int col0 = n0 + (wn << 6) + fr;
#pragma unroll
  for (int j = 0; j < 4; j++) {
    const int col = col0 + (j << 4);
    const float bv = bq[col];
#pragma unroll
    for (int i = 0; i < 4; i++) {
      const int row = row0 + (i << 4);
#pragma unroll
      for (int r = 0; r < 4; r++)
        C[(size_t)(row + r) * N + col] = acc[i][j][r] + bv;
    }
  }
}

extern "C" void kernel_launch(void* const* d_in, const int* in_sizes, int n_in,
                              void* d_out, int out_size, void* d_ws, size_t ws_size,
                              hipStream_t stream) {
  const float* x = (const float*)d_in[0];
  const float* w = (const float*)d_in[1];
  const float* bias = (const float*)d_in[2];
  float* out = (float*)d_out;

  const int out_f = in_sizes[2];                 // 2048
  const int in_f = in_sizes[1] / out_f;          // 2048
  const int m = in_sizes[0] / in_f;              // 8192
  const int k = in_f;

  // workspace layout: Xq bf16 | Wq bf16 | bq fp32
  ushort* Xq = (ushort*)d_ws;
  ushort* Wq = Xq + (size_t)m * k;
  float* bquant = (float*)(Wq + (size_t)out_f * k);

  const int nx4 = in_sizes[0] / 4;
  const int nw4 = in_sizes[1] / 4;
  const int nb4 = in_sizes[2] / 4;
  const int total4 = nx4 + nw4 + nb4;
  posit_quant_all<<<(total4 + 255) / 256, 256, 0, stream>>>(
      x, w, bias, Xq, Wq, bquant, nx4, nw4, nb4);

  dim3 grid(out_f / 256, m / 256);
  posit_gemm<<<grid, 1024, 0, stream>>>(Xq, Wq, bquant, out, m, out_f, k);
}

// Round 9
// 177.269 us; speedup vs baseline: 1.0699x; 1.0381x over previous
//
#include <hip/hip_runtime.h>

typedef __attribute__((ext_vector_type(8))) short bf16x8;
typedef __attribute__((ext_vector_type(4))) float f32x4;

// ---------------------------------------------------------------------------
// Posit(8,1) round-to-nearest posit quantization, bit-exact vs jnp reference.
// ---------------------------------------------------------------------------
__device__ __forceinline__ float posit_q(float x) {
  float ax = fabsf(x);
  ax = fmaxf(ax, 0x1p-12f);
  ax = fminf(ax, 0x1p12f);
  int s = (int)(__float_as_uint(ax) >> 23) - 127;   // floor(log2(ax)), exact
  int k = s >> 1;                                   // floor(s/2)
  int rlen = (k >= 0) ? (k + 2) : (1 - k);
  int fbits = 6 - rlen;
  fbits = fbits < 0 ? 0 : fbits;
  float m = ax * __uint_as_float((unsigned)(127 - s) << 23);  // [1,2)
  float fs = (float)(1 << fbits);
  float inv_fs = __uint_as_float((unsigned)(127 - fbits) << 23);
  float mq = rintf(m * fs) * inv_fs;                // round-half-even = jnp.round
  if (mq >= 2.0f) { s += 1; mq = 1.0f; }            // mantissa carry
  float y = mq * __uint_as_float((unsigned)(127 + s) << 23);
  y = fminf(y, 0x1p12f);
  y = copysignf(y, x);
  return (x == 0.0f) ? 0.0f : y;
}

__device__ __forceinline__ ushort4 quant4_bf16(float4 v) {
  ushort4 o;
  o.x = (ushort)(__float_as_uint(posit_q(v.x)) >> 16);
  o.y = (ushort)(__float_as_uint(posit_q(v.y)) >> 16);
  o.z = (ushort)(__float_as_uint(posit_q(v.z)) >> 16);
  o.w = (ushort)(__float_as_uint(posit_q(v.w)) >> 16);
  return o;
}

__global__ void posit_quant_all(const float* __restrict__ x,
                                const float* __restrict__ w,
                                const float* __restrict__ b,
                                ushort* __restrict__ Xq,
                                ushort* __restrict__ Wq,
                                float* __restrict__ bq,
                                int nx4, int nw4, int nb4) {
  int i = blockIdx.x * blockDim.x + threadIdx.x;
  if (i < nx4) {
    ((ushort4*)Xq)[i] = quant4_bf16(((const float4*)x)[i]);
  } else if (i < nx4 + nw4) {
    int j = i - nx4;
    ((ushort4*)Wq)[j] = quant4_bf16(((const float4*)w)[j]);
  } else if (i < nx4 + nw4 + nb4) {
    int j = i - nx4 - nw4;
    float4 v = ((const float4*)b)[j];
    float4 o;
    o.x = posit_q(v.x); o.y = posit_q(v.y);
    o.z = posit_q(v.z); o.w = posit_q(v.w);
    ((float4*)bq)[j] = o;
  }
}

// ---------------------------------------------------------------------------
// R14 = R13 resubmitted verbatim (R13 bench was an infrastructure failure:
// "MI355X container failed twice" - no kernel data).
//
// R13 design: R12 (256x256, BK=32, 5 x 32KB buffers, T1 XCD 4x8 patch
// mapping, 1024 thr = 16 waves 4x4, counted vmcnt, swizzled
// global_load_lds) with TWO K-tiles per barrier phase.
//
// Why: R12 sits at 156k cyc/CU with MFMA needing ~79k and LDS-read ~67-100k
// - two overlappable pipes each ~50% - but MfmaUtil is only 43% because all
// 16 waves are barrier-aligned: reads burst (matrix pipe idle), then MFMAs
// burst (LDS idle), x64 phases. Halve the lockstep: one barrier covers two
// K-tiles; COMP(t) and COMP(t+1) share one unfenced scheduling region so the
// compiler hoists COMP(t+1)'s ds_reads into COMP(t)'s MFMA stream (it emits
// fine-grained lgkmcnt). Barriers 64 -> 32.
//
// Wait math (4 loads/wave/phase): entry outstanding {t,t+1}=4; stage
// {t+2,t+3} -> 8; vmcnt(4) retires exactly {t,t+1}; 4 loads stay in flight
// across the barrier (never drains mid-loop, T4). Issue-to-need = one full
// phase (~4900 cyc) >> HBM latency. WAR: stage target buf[(t+2)%5] =
// buf[(t-3)%5], last read two phases back, separated by BAR(p-1). Live
// buffers = 4 consecutive of 5. Final phase: vmcnt(0), no stage.
//
// Swizzle (R10..R12-verified, 0 conflicts): chunk p of row r at slot
// p ^ ((r>>1)&3), pre-applied to the GLOBAL source (LDS dests lane-linear).
// T1 mapping (R12-verified, FETCH 135->49 MB): xcd = flat&7 owns a 4-row x
// 8-col patch: by' = xcd*4 + (r&3), bx' = r>>2.
// ---------------------------------------------------------------------------
__device__ __forceinline__ void gl_lds16(const ushort* g, ushort* l) {
  __builtin_amdgcn_global_load_lds(
      (const __attribute__((address_space(1))) void*)g,
      (__attribute__((address_space(3))) void*)l,
      16, 0, 0);
}

#define BAR() do { __builtin_amdgcn_s_barrier(); \
                   __builtin_amdgcn_sched_barrier(0); } while (0)

__global__ __launch_bounds__(1024, 4) void posit_gemm(
    const ushort* __restrict__ A, const ushort* __restrict__ B,
    const float* __restrict__ bq, float* __restrict__ C,
    int M, int N, int K) {
  __shared__ ushort lds[81920];   // 160 KiB: 5 buffers x 16384 elems (A|B 8192)

  const int tid = threadIdx.x;
  const int wave = tid >> 6;        // 0..15
  const int lane = tid & 63;
  const int wm = wave >> 2;         // 0..3 : 64-row slab
  const int wn = wave & 3;          // 0..3 : 64-col slab

  // T1: XCD patch mapping (grid 8x32, flat id x-fastest, xcd = flat&7)
  const int flat = (blockIdx.y << 3) | blockIdx.x;
  const int xcd = flat & 7;
  const int rr = flat >> 3;                 // 0..31
  const int m0 = ((xcd << 2) + (rr & 3)) << 8;   // row-tile 4*xcd + r%4
  const int n0 = (rr >> 2) << 8;                 // col-tile r/4

  // --- staging: one A + one B instruction per wave per K-tile; instruction
  // covers 16 rows (wave*16 + lane>>2), 4 lanes per row = 4 chunks of 8.
  // Source chunk pre-swizzled: (lane&3) ^ ((row>>1)&3) = (lane&3)^((lane>>3)&3).
  const int srow = (wave << 4) + (lane >> 2);         // 0..255
  const int sk = (((lane & 3) ^ ((lane >> 3) & 3)) << 3);
  const ushort* Ag = A + (size_t)(m0 + srow) * K + sk;
  const ushort* Bg = B + (size_t)(n0 + srow) * K + sk;
  const int sbase = wave << 9;                        // wave*512 elems

#define STAGE(Lb, kt) do {                                         \
    gl_lds16(Ag + ((size_t)(kt) << 5), (Lb) + sbase);              \
    gl_lds16(Bg + ((size_t)(kt) << 5), (Lb) + 8192 + sbase);       \
  } while (0)

  // --- fragment reads: row = slab + i*16 + fr; needed chunk t4 at slot
  // t4 ^ ((fr>>1)&3).
  const int fr = lane & 15;
  const int t4 = lane >> 4;                           // 0..3
  const int sl = ((t4 ^ ((fr >> 1) & 3)) << 3);
  const int arl = (((wm << 6) + fr) << 5) + sl;        // + i*512
  const int brl = (((wn << 6) + fr) << 5) + sl + 8192; // + j*512

  f32x4 acc[4][4];
#pragma unroll
  for (int i = 0; i < 4; i++)
#pragma unroll
    for (int j = 0; j < 4; j++) acc[i][j] = (f32x4){0.f, 0.f, 0.f, 0.f};

#define COMP(Lb) do {                                              \
    bf16x8 fa[4], fb[4];                                           \
    _Pragma("unroll")                                              \
    for (int i = 0; i < 4; i++)                                    \
      fa[i] = *(const bf16x8*)((Lb) + arl + (i << 9));             \
    _Pragma("unroll")                                              \
    for (int j = 0; j < 4; j++)                                    \
      fb[j] = *(const bf16x8*)((Lb) + brl + (j << 9));             \
    _Pragma("unroll")                                              \
    for (int i = 0; i < 4; i++)                                    \
      _Pragma("unroll")                                            \
      for (int j = 0; j < 4; j++)                                  \
        acc[i][j] = __builtin_amdgcn_mfma_f32_16x16x32_bf16(       \
            fa[i], fb[j], acc[i][j], 0, 0, 0);                     \
  } while (0)

  const int T = K >> 5;               // 64 K-tiles of 32 (even)

  // ---- prologue: t0->buf0, t1->buf1 (4 loads outstanding)
  STAGE(lds,         0);
  STAGE(lds + 16384, 1);

  int t = 0;
  int ai = 0;                         // t   mod 5 (compute buffers ai, ai+1)
  int ci = 2;                         // t+2 mod 5 (stage buffers ci, ci+1)
#pragma unroll 1
  for (; t < T - 2; t += 2) {
    const int bi = (ai == 4) ? 0 : ai + 1;
    const int di = (ci == 4) ? 0 : ci + 1;
    STAGE(lds + (ci << 14), t + 2);
    STAGE(lds + (di << 14), t + 3);
    asm volatile("s_waitcnt vmcnt(4)" ::: "memory");  // {t,t+1} landed
    BAR();
    COMP(lds + (ai << 14));
    COMP(lds + (bi << 14));
    ai = (ai + 2 >= 5) ? ai - 3 : ai + 2;
    ci = (ci + 2 >= 5) ? ci - 3 : ci + 2;
  }
  // ---- final phase: tiles T-2, T-1 (no stage)
  {
    const int bi = (ai == 4) ? 0 : ai + 1;
    asm volatile("s_waitcnt vmcnt(0)" ::: "memory");
    BAR();
    COMP(lds + (ai << 14));
    COMP(lds + (bi << 14));
  }

  // Epilogue: C/D layout col = lane&15, row = (lane>>4)*4 + reg. Fuse bias.
  const int row0 = m0 + (wm << 6) + (t4 << 2);
  const int col0 = n0 + (wn << 6) + fr;
#pragma unroll
  for (int j = 0; j < 4; j++) {
    const int col = col0 + (j << 4);
    const float bv = bq[col];
#pragma unroll
    for (int i = 0; i < 4; i++) {
      const int row = row0 + (i << 4);
#pragma unroll
      for (int r = 0; r < 4; r++)
        C[(size_t)(row + r) * N + col] = acc[i][j][r] + bv;
    }
  }
}

extern "C" void kernel_launch(void* const* d_in, const int* in_sizes, int n_in,
                              void* d_out, int out_size, void* d_ws, size_t ws_size,
                              hipStream_t stream) {
  const float* x = (const float*)d_in[0];
  const float* w = (const float*)d_in[1];
  const float* bias = (const float*)d_in[2];
  float* out = (float*)d_out;

  const int out_f = in_sizes[2];                 // 2048
  const int in_f = in_sizes[1] / out_f;          // 2048
  const int m = in_sizes[0] / in_f;              // 8192
  const int k = in_f;

  // workspace layout: Xq bf16 | Wq bf16 | bq fp32
  ushort* Xq = (ushort*)d_ws;
  ushort* Wq = Xq + (size_t)m * k;
  float* bquant = (float*)(Wq + (size_t)out_f * k);

  const int nx4 = in_sizes[0] / 4;
  const int nw4 = in_sizes[1] / 4;
  const int nb4 = in_sizes[2] / 4;
  const int total4 = nx4 + nw4 + nb4;
  posit_quant_all<<<(total4 + 255) / 256, 256, 0, stream>>>(
      x, w, bias, Xq, Wq, bquant, nx4, nw4, nb4);

  dim3 grid(out_f / 256, m / 256);
  posit_gemm<<<grid, 1024, 0, stream>>>(Xq, Wq, bquant, out, m, out_f, k);
}